// Round 1
// baseline (724.831 us; speedup 1.0000x reference)
//
#include <hip/hip_runtime.h>

typedef unsigned short u16;
typedef __attribute__((ext_vector_type(8))) short bf16x8;
typedef __attribute__((ext_vector_type(4))) float f32x4;
typedef __attribute__((ext_vector_type(4))) unsigned short u16x4;

__device__ __forceinline__ u16 f2bf(float f) {
  union { float f; unsigned u; } v; v.f = f;
  return (u16)((v.u + 0x7FFFu + ((v.u >> 16) & 1u)) >> 16);
}

__device__ __forceinline__ void gload16(const u16* g, u16* l) {
  __builtin_amdgcn_global_load_lds((const __attribute__((address_space(1))) void*)g,
                                   (__attribute__((address_space(3))) void*)l, 16, 0, 0);
}

// ---------------- fp32 -> bf16 convert ----------------
__global__ __launch_bounds__(256) void k_f2bf(const float* __restrict__ in,
                                              u16* __restrict__ out, int n4) {
  int i = blockIdx.x * 256 + threadIdx.x;
  const int stride = gridDim.x * 256;
  for (; i < n4; i += stride) {
    const float4 v = ((const float4*)in)[i];
    u16x4 o;
    o.x = f2bf(v.x); o.y = f2bf(v.y); o.z = f2bf(v.z); o.w = f2bf(v.w);
    ((u16x4*)out)[i] = o;
  }
}

// ---------------- GEMM: C[M,N] = A[M,K] * Bt[N,K]^T + bias[N] ----------------
// 128x128 tile, BK=64, 256 threads (2x2 waves, 64x64 per wave, 4x4 16x16 frags).
template <int OUT_F32>
__global__ __launch_bounds__(256) void k_gemm_bias(
    const u16* __restrict__ A, const u16* __restrict__ Bt, const float* __restrict__ bias,
    u16* __restrict__ Cb, float* __restrict__ Cf, int M, int N, int K)
{
  __shared__ u16 As[128 * 64];
  __shared__ u16 Bs[128 * 64];
  const int tid = threadIdx.x;
  const int lane = tid & 63;
  const int wid = tid >> 6;
  const int fr = lane & 15;        // row within 16-tile (A/B operand), col of C/D
  const int fg = lane >> 4;        // k-group (A/B operand), row-group of C/D
  const int wr = wid >> 1, wc = wid & 1;
  const long row0 = (long)blockIdx.x * 128;
  const long col0 = (long)blockIdx.y * 128;

  f32x4 acc[4][4] = {};

  for (int k0 = 0; k0 < K; k0 += 64) {
    __syncthreads();   // previous iteration's LDS reads done
#pragma unroll
    for (int i = 0; i < 4; ++i) {
      const int chunk = (wid * 4 + i) * 64 + lane;     // 16B chunk id, 0..1023
      const int r = chunk >> 3;                        // tile row (8 chunks per 64-elem row)
      const int c = (chunk & 7) << 3;                  // col (elements)
      gload16(A + (row0 + r) * (long)K + k0 + c, &As[(wid * 4 + i) * 512]);
      gload16(Bt + (col0 + r) * (long)K + k0 + c, &Bs[(wid * 4 + i) * 512]);
    }
    __syncthreads();   // loads landed (vmcnt drained before barrier)

#pragma unroll
    for (int kc = 0; kc < 2; ++kc) {
      bf16x8 a[4], b[4];
#pragma unroll
      for (int i = 0; i < 4; ++i)
        a[i] = *(const bf16x8*)&As[(wr * 64 + i * 16 + fr) * 64 + kc * 32 + fg * 8];
#pragma unroll
      for (int j = 0; j < 4; ++j)
        b[j] = *(const bf16x8*)&Bs[(wc * 64 + j * 16 + fr) * 64 + kc * 32 + fg * 8];
#pragma unroll
      for (int i = 0; i < 4; ++i)
#pragma unroll
        for (int j = 0; j < 4; ++j)
          acc[i][j] = __builtin_amdgcn_mfma_f32_16x16x32_bf16(a[i], b[j], acc[i][j], 0, 0, 0);
    }
  }

  // epilogue: C/D layout col = lane&15, row = (lane>>4)*4 + reg
#pragma unroll
  for (int j = 0; j < 4; ++j) {
    const long cN = col0 + wc * 64 + j * 16 + fr;
    const float bv = bias[cN];
#pragma unroll
    for (int i = 0; i < 4; ++i) {
      const long rM = row0 + wr * 64 + i * 16 + fg * 4;
#pragma unroll
      for (int reg = 0; reg < 4; ++reg) {
        const float v = acc[i][j][reg] + bv;
        if (OUT_F32) Cf[(rM + reg) * N + cN] = v;
        else         Cb[(rM + reg) * N + cN] = f2bf(v);
      }
    }
  }
}

// ---------------- V transpose: V[b][s][h*128+d] -> Vt[(b*16+h)*128+d][s] ----------------
__global__ __launch_bounds__(256) void k_transpose_v(const u16* __restrict__ V,
                                                     u16* __restrict__ Vt) {
  __shared__ u16 t[64][68];
  const int bh = blockIdx.z;
  const long s0 = (long)blockIdx.x * 64;
  const long d0 = (long)blockIdx.y * 64;
  const int tid = threadIdx.x;
  const long rowbase = (long)(bh >> 4) * 2048;
  const int hcol = (bh & 15) * 128;
#pragma unroll
  for (int i = 0; i < 4; ++i) {
    const int v = tid + i * 256;               // 0..1023 4-vectors
    const int r = v >> 4, c4 = (v & 15) << 2;
    const u16x4 val = *(const u16x4*)&V[(rowbase + s0 + r) * 2048 + hcol + d0 + c4];
    *(u16x4*)&t[r][c4] = val;
  }
  __syncthreads();
#pragma unroll
  for (int i = 0; i < 4; ++i) {
    const int v = tid + i * 256;
    const int dr = v >> 4, s4 = (v & 15) << 2;
    u16x4 o;
    o.x = t[s4 + 0][dr]; o.y = t[s4 + 1][dr]; o.z = t[s4 + 2][dr]; o.w = t[s4 + 3][dr];
    *(u16x4*)&Vt[((long)bh * 128 + d0 + dr) * 2048 + s0 + s4] = o;
  }
}

// ---------------- causal flash attention ----------------
// grid: (S/64, B*H). 4 waves; wave owns 16 q rows. KVBLK=64, D=128.
__global__ __launch_bounds__(256) void k_flash_attn(
    const u16* __restrict__ Q, const u16* __restrict__ K, const u16* __restrict__ Vt,
    u16* __restrict__ O)
{
  const int lane = threadIdx.x & 63, wid = threadIdx.x >> 6;
  const int fr = lane & 15, fg = lane >> 4;
  const int qblk = blockIdx.x;
  const int bh = blockIdx.y;
  const long rowbase = (long)(bh >> 4) * 2048;
  const int hcol = (bh & 15) * 128;
  const int q0 = qblk * 64 + wid * 16;

  __shared__ u16 Plds[4][16][72];   // per-wave P tile, padded stride

  // Q fragments (A-operand): lane holds row fr, k = c*32 + fg*8
  bf16x8 qf[4];
#pragma unroll
  for (int c = 0; c < 4; ++c)
    qf[c] = *(const bf16x8*)&Q[(rowbase + q0 + fr) * 2048 + hcol + c * 32 + fg * 8];

  f32x4 oacc[8] = {};
  float m_run[4], l_run[4];
#pragma unroll
  for (int r = 0; r < 4; ++r) { m_run[r] = -1e30f; l_run[r] = 0.0f; }

  const float scale = 0.08838834764831845f;   // 1/sqrt(128)
  const int nkv = qblk + 1;
  for (int j = 0; j < nkv; ++j) {
    const int kv0 = j * 64;
    // S = Q K^T over D=128: 4 k-tiles x 4 k-chunks
    f32x4 st[4] = {};
#pragma unroll
    for (int t = 0; t < 4; ++t) {
#pragma unroll
      for (int c = 0; c < 4; ++c) {
        const bf16x8 kf = *(const bf16x8*)
            &K[(rowbase + kv0 + t * 16 + fr) * 2048 + hcol + c * 32 + fg * 8];
        st[t] = __builtin_amdgcn_mfma_f32_16x16x32_bf16(qf[c], kf, st[t], 0, 0, 0);
      }
    }
    // scale + causal mask + row max
    float mx[4] = {-1e30f, -1e30f, -1e30f, -1e30f};
#pragma unroll
    for (int t = 0; t < 4; ++t) {
      const int kg = kv0 + t * 16 + fr;
#pragma unroll
      for (int r = 0; r < 4; ++r) {
        const int qg = q0 + fg * 4 + r;
        const float s = (kg <= qg) ? st[t][r] * scale : -1e30f;
        st[t][r] = s;
        mx[r] = fmaxf(mx[r], s);
      }
    }
#pragma unroll
    for (int d = 1; d < 16; d <<= 1)
#pragma unroll
      for (int r = 0; r < 4; ++r) mx[r] = fmaxf(mx[r], __shfl_xor(mx[r], d));

    float alpha[4], lsum[4] = {0, 0, 0, 0};
#pragma unroll
    for (int r = 0; r < 4; ++r) {
      const float nm = fmaxf(m_run[r], mx[r]);
      alpha[r] = __expf(m_run[r] - nm);
      m_run[r] = nm;
    }
#pragma unroll
    for (int t = 0; t < 4; ++t)
#pragma unroll
      for (int r = 0; r < 4; ++r) {
        const float p = __expf(st[t][r] - m_run[r]);
        st[t][r] = p;
        lsum[r] += p;
      }
#pragma unroll
    for (int d = 1; d < 16; d <<= 1)
#pragma unroll
      for (int r = 0; r < 4; ++r) lsum[r] += __shfl_xor(lsum[r], d);
#pragma unroll
    for (int r = 0; r < 4; ++r) l_run[r] = l_run[r] * alpha[r] + lsum[r];
#pragma unroll
    for (int dt = 0; dt < 8; ++dt)
#pragma unroll
      for (int r = 0; r < 4; ++r) oacc[dt][r] *= alpha[r];

    // P (C/D layout) -> LDS in A-operand layout
#pragma unroll
    for (int t = 0; t < 4; ++t)
#pragma unroll
      for (int r = 0; r < 4; ++r)
        Plds[wid][fg * 4 + r][t * 16 + fr] = f2bf(st[t][r]);
    __syncthreads();   // uniform trip count across waves; orders P write->read

    // O += P * V  (B-operand: Vt row d = dt*16+fr, contiguous k)
#pragma unroll
    for (int kc = 0; kc < 2; ++kc) {
      const bf16x8 pf = *(const bf16x8*)&Plds[wid][fr][kc * 32 + fg * 8];
#pragma unroll
      for (int dt = 0; dt < 8; ++dt) {
        const bf16x8 vf = *(const bf16x8*)
            &Vt[((long)bh * 128 + dt * 16 + fr) * 2048 + kv0 + kc * 32 + fg * 8];
        oacc[dt] = __builtin_amdgcn_mfma_f32_16x16x32_bf16(pf, vf, oacc[dt], 0, 0, 0);
      }
    }
  }

  float inv[4];
#pragma unroll
  for (int r = 0; r < 4; ++r) inv[r] = 1.0f / l_run[r];
#pragma unroll
  for (int dt = 0; dt < 8; ++dt)
#pragma unroll
    for (int r = 0; r < 4; ++r)
      O[(rowbase + q0 + fg * 4 + r) * 2048 + hcol + dt * 16 + fr] = f2bf(oacc[dt][r] * inv[r]);
}

extern "C" void kernel_launch(void* const* d_in, const int* in_sizes, int n_in,
                              void* d_out, int out_size, void* d_ws, size_t ws_size,
                              hipStream_t stream) {
  const float* x  = (const float*)d_in[0];
  const float* Wq = (const float*)d_in[1];
  const float* bq = (const float*)d_in[2];
  const float* Wk = (const float*)d_in[3];
  const float* bk = (const float*)d_in[4];
  const float* Wv = (const float*)d_in[5];
  const float* bv = (const float*)d_in[6];
  const float* Wo = (const float*)d_in[7];
  const float* bo = (const float*)d_in[8];
  float* out = (float*)d_out;

  const int M = 4096, N = 2048, Kd = 2048;
  char* ws = (char*)d_ws;
  const size_t SZ_X = 16777216;   // 8M bf16
  const size_t SZ_W = 8388608;    // 4M bf16
  u16* xb  = (u16*)(ws);
  u16* wqb = (u16*)(ws + SZ_X);
  u16* wkb = (u16*)(ws + SZ_X + 1 * SZ_W);
  u16* wvb = (u16*)(ws + SZ_X + 2 * SZ_W);
  u16* wob = (u16*)(ws + SZ_X + 3 * SZ_W);
  u16* Qb  = (u16*)(ws + 1 * SZ_X + 4 * SZ_W);
  u16* Kb  = (u16*)(ws + 2 * SZ_X + 4 * SZ_W);
  u16* Vb  = (u16*)(ws + 3 * SZ_X + 4 * SZ_W);
  u16* Vtb = (u16*)(ws + 4 * SZ_X + 4 * SZ_W);
  u16* Ob  = Vb;   // V dead after transpose; reuse for attention output

  k_f2bf<<<2048, 256, 0, stream>>>(x,  xb,  8388608 / 4);
  k_f2bf<<<1024, 256, 0, stream>>>(Wq, wqb, 4194304 / 4);
  k_f2bf<<<1024, 256, 0, stream>>>(Wk, wkb, 4194304 / 4);
  k_f2bf<<<1024, 256, 0, stream>>>(Wv, wvb, 4194304 / 4);
  k_f2bf<<<1024, 256, 0, stream>>>(Wo, wob, 4194304 / 4);

  dim3 gg(M / 128, N / 128);
  k_gemm_bias<0><<<gg, 256, 0, stream>>>(xb, wqb, bq, Qb, nullptr, M, N, Kd);
  k_gemm_bias<0><<<gg, 256, 0, stream>>>(xb, wkb, bk, Kb, nullptr, M, N, Kd);
  k_gemm_bias<0><<<gg, 256, 0, stream>>>(xb, wvb, bv, Vb, nullptr, M, N, Kd);

  k_transpose_v<<<dim3(32, 2, 32), 256, 0, stream>>>(Vb, Vtb);

  k_flash_attn<<<dim3(32, 32), 256, 0, stream>>>(Qb, Kb, Vtb, Ob);

  k_gemm_bias<1><<<gg, 256, 0, stream>>>(Ob, wob, bo, nullptr, out, M, N, Kd);
}

// Round 2
// 320.729 us; speedup vs baseline: 2.2599x; 2.2599x over previous
//
#include <hip/hip_runtime.h>

typedef unsigned short u16;
typedef __attribute__((ext_vector_type(8))) short bf16x8;
typedef __attribute__((ext_vector_type(4))) float f32x4;
typedef __attribute__((ext_vector_type(4))) unsigned short u16x4;

__device__ __forceinline__ u16 f2bf(float f) {
  union { float f; unsigned u; } v; v.f = f;
  return (u16)((v.u + 0x7FFFu + ((v.u >> 16) & 1u)) >> 16);
}

__device__ __forceinline__ void gload16(const u16* g, u16* l) {
  __builtin_amdgcn_global_load_lds((const __attribute__((address_space(1))) void*)g,
                                   (__attribute__((address_space(3))) void*)l, 16, 0, 0);
}

// ---------------- fp32 -> bf16 convert (5 tensors fused) ----------------
__global__ __launch_bounds__(256) void k_f2bf5(
    const float* __restrict__ i0, const float* __restrict__ i1, const float* __restrict__ i2,
    const float* __restrict__ i3, const float* __restrict__ i4,
    u16* o0, u16* o1, u16* o2, u16* o3, u16* o4, int n4x, int n4w) {
  const int seg = blockIdx.y;
  const float* in = (seg == 0) ? i0 : (seg == 1) ? i1 : (seg == 2) ? i2 : (seg == 3) ? i3 : i4;
  u16* out = (seg == 0) ? o0 : (seg == 1) ? o1 : (seg == 2) ? o2 : (seg == 3) ? o3 : o4;
  const int n4 = (seg == 0) ? n4x : n4w;
  int i = blockIdx.x * 256 + threadIdx.x;
  const int stride = gridDim.x * 256;
  for (; i < n4; i += stride) {
    const float4 v = ((const float4*)in)[i];
    u16x4 o;
    o.x = f2bf(v.x); o.y = f2bf(v.y); o.z = f2bf(v.z); o.w = f2bf(v.w);
    ((u16x4*)out)[i] = o;
  }
}

// ---------------- GEMM: C[M,N] = A[M,K] * Bt[N,K]^T + bias[N] ----------------
template <int OUT_F32>
__global__ __launch_bounds__(256) void k_gemm_bias(
    const u16* __restrict__ A, const u16* __restrict__ Bt, const float* __restrict__ bias,
    u16* __restrict__ Cb, float* __restrict__ Cf, int M, int N, int K)
{
  __shared__ u16 As[128 * 64];
  __shared__ u16 Bs[128 * 64];
  const int tid = threadIdx.x;
  const int lane = tid & 63;
  const int wid = tid >> 6;
  const int fr = lane & 15;
  const int fg = lane >> 4;
  const int wr = wid >> 1, wc = wid & 1;
  const long row0 = (long)blockIdx.x * 128;
  const long col0 = (long)blockIdx.y * 128;

  f32x4 acc[4][4] = {};

  for (int k0 = 0; k0 < K; k0 += 64) {
    __syncthreads();
#pragma unroll
    for (int i = 0; i < 4; ++i) {
      const int chunk = (wid * 4 + i) * 64 + lane;
      const int r = chunk >> 3;
      const int c = (chunk & 7) << 3;
      gload16(A + (row0 + r) * (long)K + k0 + c, &As[(wid * 4 + i) * 512]);
      gload16(Bt + (col0 + r) * (long)K + k0 + c, &Bs[(wid * 4 + i) * 512]);
    }
    __syncthreads();

#pragma unroll
    for (int kc = 0; kc < 2; ++kc) {
      bf16x8 a[4], b[4];
#pragma unroll
      for (int i = 0; i < 4; ++i)
        a[i] = *(const bf16x8*)&As[(wr * 64 + i * 16 + fr) * 64 + kc * 32 + fg * 8];
#pragma unroll
      for (int j = 0; j < 4; ++j)
        b[j] = *(const bf16x8*)&Bs[(wc * 64 + j * 16 + fr) * 64 + kc * 32 + fg * 8];
#pragma unroll
      for (int i = 0; i < 4; ++i)
#pragma unroll
        for (int j = 0; j < 4; ++j)
          acc[i][j] = __builtin_amdgcn_mfma_f32_16x16x32_bf16(a[i], b[j], acc[i][j], 0, 0, 0);
    }
  }

#pragma unroll
  for (int j = 0; j < 4; ++j) {
    const long cN = col0 + wc * 64 + j * 16 + fr;
    const float bv = bias[cN];
#pragma unroll
    for (int i = 0; i < 4; ++i) {
      const long rM = row0 + wr * 64 + i * 16 + fg * 4;
#pragma unroll
      for (int reg = 0; reg < 4; ++reg) {
        const float v = acc[i][j][reg] + bv;
        if (OUT_F32) Cf[(rM + reg) * N + cN] = v;
        else         Cb[(rM + reg) * N + cN] = f2bf(v);
      }
    }
  }
}

// ---------------- V transpose: V[b][s][h*128+d] -> Vt[(b*16+h)*128+d][s] ----------------
__global__ __launch_bounds__(256) void k_transpose_v(const u16* __restrict__ V,
                                                     u16* __restrict__ Vt) {
  __shared__ u16 t[64][68];
  const int bh = blockIdx.z;
  const long s0 = (long)blockIdx.x * 64;
  const long d0 = (long)blockIdx.y * 64;
  const int tid = threadIdx.x;
  const long rowbase = (long)(bh >> 4) * 2048;
  const int hcol = (bh & 15) * 128;
#pragma unroll
  for (int i = 0; i < 4; ++i) {
    const int v = tid + i * 256;
    const int r = v >> 4, c4 = (v & 15) << 2;
    const u16x4 val = *(const u16x4*)&V[(rowbase + s0 + r) * 2048 + hcol + d0 + c4];
    *(u16x4*)&t[r][c4] = val;
  }
  __syncthreads();
#pragma unroll
  for (int i = 0; i < 4; ++i) {
    const int v = tid + i * 256;
    const int dr = v >> 4, s4 = (v & 15) << 2;
    u16x4 o;
    o.x = t[s4 + 0][dr]; o.y = t[s4 + 1][dr]; o.z = t[s4 + 2][dr]; o.w = t[s4 + 3][dr];
    *(u16x4*)&Vt[((long)bh * 128 + d0 + dr) * 2048 + s0 + s4] = o;
  }
}

// ---------------- causal flash attention, LDS-staged + swizzled + paired ----------------
// grid (16, 32): block handles q-blocks bx and 31-bx (uniform 33 kv-steps).
// 4 waves x 16 q-rows. K tile [64][128] (16 16B-chunks/row), Vt tile [128][64] (8/row).
// XOR swizzle: 16B-chunk index ^= (row & 7); inverse applied on global source addr.
__global__ __launch_bounds__(256) void k_flash_attn(
    const u16* __restrict__ Q, const u16* __restrict__ K, const u16* __restrict__ Vt,
    u16* __restrict__ O)
{
  __shared__ alignas(16) u16 Kt[2][8192];
  __shared__ alignas(16) u16 Vtt[2][8192];
  __shared__ alignas(16) u16 Plds[4][16][72];

  const int tid = threadIdx.x;
  const int lane = tid & 63, wid = tid >> 6;
  const int fr = lane & 15, fg = lane >> 4;
  const int bh = blockIdx.y;
  const long rowbase = (long)(bh >> 4) * 2048;
  const int hcol = (bh & 15) * 128;
  const u16* Kg = K + rowbase * 2048 + hcol;          // + row*2048 + col
  const u16* Vg = Vt + (long)bh * 128 * 2048;          // + d*2048 + s
  const float scale = 0.08838834764831845f;            // 1/sqrt(128)

  // staging constants: 4 chunk-groups per wave per tile
  int kR[4], kC[4], vR[4], vC[4];
#pragma unroll
  for (int i = 0; i < 4; ++i) {
    const int chunk = (wid * 4 + i) * 64 + lane;
    kR[i] = chunk >> 4;                                 // K tile: 16 chunks/row
    kC[i] = (((chunk & 15) ^ (kR[i] & 7)) << 3);
    vR[i] = chunk >> 3;                                 // Vt tile: 8 chunks/row
    vC[i] = (((chunk & 7) ^ (vR[i] & 7)) << 3);
  }

  for (int pass = 0; pass < 2; ++pass) {
    const int qblk = pass ? (31 - (int)blockIdx.x) : (int)blockIdx.x;
    const int q0 = qblk * 64 + wid * 16;
    const int n = qblk + 1;

    bf16x8 qf[4];
#pragma unroll
    for (int c = 0; c < 4; ++c)
      qf[c] = *(const bf16x8*)&Q[(rowbase + q0 + fr) * 2048 + hcol + c * 32 + fg * 8];

    f32x4 oacc[8] = {};
    float m_run[4], l_run[4];
#pragma unroll
    for (int r = 0; r < 4; ++r) { m_run[r] = -1e30f; l_run[r] = 0.0f; }

    // prologue: stage kv-step 0 into buffer 0
#pragma unroll
    for (int i = 0; i < 4; ++i) {
      gload16(Kg + (long)kR[i] * 2048 + kC[i], &Kt[0][(wid * 4 + i) * 512]);
      gload16(Vg + (long)vR[i] * 2048 + vC[i], &Vtt[0][(wid * 4 + i) * 512]);
    }

    int cur = 0;
    for (int j = 0; j < n; ++j) {
      if (j + 1 < n) {
        const long kvn = (long)(j + 1) * 64;
#pragma unroll
        for (int i = 0; i < 4; ++i) {
          gload16(Kg + (kvn + kR[i]) * 2048 + kC[i], &Kt[cur ^ 1][(wid * 4 + i) * 512]);
          gload16(Vg + (long)vR[i] * 2048 + kvn + vC[i], &Vtt[cur ^ 1][(wid * 4 + i) * 512]);
        }
        asm volatile("s_waitcnt vmcnt(8)" ::: "memory");
      } else {
        asm volatile("s_waitcnt vmcnt(0)" ::: "memory");
      }
      __builtin_amdgcn_s_barrier();
      __builtin_amdgcn_sched_barrier(0);

      // ---- QK^T from swizzled LDS ----
      const int kv0 = j * 64;
      f32x4 st[4] = {};
      const u16* kt = Kt[cur];
#pragma unroll
      for (int t = 0; t < 4; ++t) {
        const int rowK = t * 16 + fr;
        const int rb = rowK * 128;
        const int sw = rowK & 7;
#pragma unroll
        for (int c = 0; c < 4; ++c) {
          const bf16x8 kf = *(const bf16x8*)&kt[rb + ((((c << 2) + fg) ^ sw) << 3)];
          st[t] = __builtin_amdgcn_mfma_f32_16x16x32_bf16(qf[c], kf, st[t], 0, 0, 0);
        }
      }

      // ---- scale + causal mask + row max ----
      float mx[4] = {-1e30f, -1e30f, -1e30f, -1e30f};
#pragma unroll
      for (int t = 0; t < 4; ++t) {
        const int kg = kv0 + t * 16 + fr;
#pragma unroll
        for (int r = 0; r < 4; ++r) {
          const int qg = q0 + fg * 4 + r;
          const float s = (kg <= qg) ? st[t][r] * scale : -1e30f;
          st[t][r] = s;
          mx[r] = fmaxf(mx[r], s);
        }
      }
#pragma unroll
      for (int d = 1; d < 16; d <<= 1)
#pragma unroll
        for (int r = 0; r < 4; ++r) mx[r] = fmaxf(mx[r], __shfl_xor(mx[r], d));

      float alpha[4], lsum[4] = {0, 0, 0, 0};
#pragma unroll
      for (int r = 0; r < 4; ++r) {
        const float nm = fmaxf(m_run[r], mx[r]);
        alpha[r] = __expf(m_run[r] - nm);
        m_run[r] = nm;
      }
#pragma unroll
      for (int t = 0; t < 4; ++t)
#pragma unroll
        for (int r = 0; r < 4; ++r) {
          const float p = __expf(st[t][r] - m_run[r]);
          st[t][r] = p;
          lsum[r] += p;
        }
#pragma unroll
      for (int d = 1; d < 16; d <<= 1)
#pragma unroll
        for (int r = 0; r < 4; ++r) lsum[r] += __shfl_xor(lsum[r], d);
#pragma unroll
      for (int r = 0; r < 4; ++r) l_run[r] = l_run[r] * alpha[r] + lsum[r];
#pragma unroll
      for (int dt = 0; dt < 8; ++dt)
#pragma unroll
        for (int r = 0; r < 4; ++r) oacc[dt][r] *= alpha[r];

      // ---- P (C/D layout) -> per-wave LDS in A-operand layout ----
#pragma unroll
      for (int t = 0; t < 4; ++t)
#pragma unroll
        for (int r = 0; r < 4; ++r)
          Plds[wid][fg * 4 + r][t * 16 + fr] = f2bf(st[t][r]);
      asm volatile("s_waitcnt lgkmcnt(0)" ::: "memory");
      __builtin_amdgcn_sched_barrier(0);

      // ---- O += P * V from swizzled LDS ----
      const u16* vt = Vtt[cur];
#pragma unroll
      for (int kc = 0; kc < 2; ++kc) {
        const bf16x8 pf = *(const bf16x8*)&Plds[wid][fr][kc * 32 + fg * 8];
#pragma unroll
        for (int dt = 0; dt < 8; ++dt) {
          const int rowV = dt * 16 + fr;
          const bf16x8 vf = *(const bf16x8*)&vt[rowV * 64 + ((((kc << 2) + fg) ^ (rowV & 7)) << 3)];
          oacc[dt] = __builtin_amdgcn_mfma_f32_16x16x32_bf16(pf, vf, oacc[dt], 0, 0, 0);
        }
      }

      asm volatile("" ::: "memory");
      __builtin_amdgcn_s_barrier();   // all waves done reading buf[cur]
      cur ^= 1;
    }

    float inv[4];
#pragma unroll
    for (int r = 0; r < 4; ++r) inv[r] = 1.0f / l_run[r];
#pragma unroll
    for (int dt = 0; dt < 8; ++dt)
#pragma unroll
      for (int r = 0; r < 4; ++r)
        O[(rowbase + q0 + fg * 4 + r) * 2048 + hcol + dt * 16 + fr] = f2bf(oacc[dt][r] * inv[r]);
  }
}

extern "C" void kernel_launch(void* const* d_in, const int* in_sizes, int n_in,
                              void* d_out, int out_size, void* d_ws, size_t ws_size,
                              hipStream_t stream) {
  const float* x  = (const float*)d_in[0];
  const float* Wq = (const float*)d_in[1];
  const float* bq = (const float*)d_in[2];
  const float* Wk = (const float*)d_in[3];
  const float* bk = (const float*)d_in[4];
  const float* Wv = (const float*)d_in[5];
  const float* bv = (const float*)d_in[6];
  const float* Wo = (const float*)d_in[7];
  const float* bo = (const float*)d_in[8];
  float* out = (float*)d_out;

  const int M = 4096, N = 2048, Kd = 2048;
  char* ws = (char*)d_ws;
  const size_t SZ_X = 16777216;   // 8M bf16
  const size_t SZ_W = 8388608;    // 4M bf16
  u16* xb  = (u16*)(ws);
  u16* wqb = (u16*)(ws + SZ_X);
  u16* wkb = (u16*)(ws + SZ_X + 1 * SZ_W);
  u16* wvb = (u16*)(ws + SZ_X + 2 * SZ_W);
  u16* wob = (u16*)(ws + SZ_X + 3 * SZ_W);
  u16* Qb  = (u16*)(ws + 1 * SZ_X + 4 * SZ_W);
  u16* Kb  = (u16*)(ws + 2 * SZ_X + 4 * SZ_W);
  u16* Vb  = (u16*)(ws + 3 * SZ_X + 4 * SZ_W);
  u16* Vtb = (u16*)(ws + 4 * SZ_X + 4 * SZ_W);
  u16* Ob  = Vb;   // V dead after transpose; reuse for attention output

  k_f2bf5<<<dim3(1024, 5), 256, 0, stream>>>(x, Wq, Wk, Wv, Wo,
                                             xb, wqb, wkb, wvb, wob,
                                             8388608 / 4, 4194304 / 4);

  dim3 gg(M / 128, N / 128);
  k_gemm_bias<0><<<gg, 256, 0, stream>>>(xb, wqb, bq, Qb, nullptr, M, N, Kd);
  k_gemm_bias<0><<<gg, 256, 0, stream>>>(xb, wkb, bk, Kb, nullptr, M, N, Kd);
  k_gemm_bias<0><<<gg, 256, 0, stream>>>(xb, wvb, bv, Vb, nullptr, M, N, Kd);

  k_transpose_v<<<dim3(32, 2, 32), 256, 0, stream>>>(Vb, Vtb);

  k_flash_attn<<<dim3(16, 32), 256, 0, stream>>>(Qb, Kb, Vtb, Ob);

  k_gemm_bias<1><<<gg, 256, 0, stream>>>(Ob, wob, bo, nullptr, out, M, N, Kd);
}

// Round 3
// 313.393 us; speedup vs baseline: 2.3128x; 1.0234x over previous
//
#include <hip/hip_runtime.h>

typedef unsigned short u16;
typedef __attribute__((ext_vector_type(8))) short bf16x8;
typedef __attribute__((ext_vector_type(4))) float f32x4;
typedef __attribute__((ext_vector_type(4))) unsigned short u16x4;

__device__ __forceinline__ u16 f2bf(float f) {
  union { float f; unsigned u; } v; v.f = f;
  return (u16)((v.u + 0x7FFFu + ((v.u >> 16) & 1u)) >> 16);
}

__device__ __forceinline__ void gload16(const u16* g, u16* l) {
  __builtin_amdgcn_global_load_lds((const __attribute__((address_space(1))) void*)g,
                                   (__attribute__((address_space(3))) void*)l, 16, 0, 0);
}

// ---------------- fp32 -> bf16 convert (5 tensors fused) ----------------
__global__ __launch_bounds__(256) void k_f2bf5(
    const float* __restrict__ i0, const float* __restrict__ i1, const float* __restrict__ i2,
    const float* __restrict__ i3, const float* __restrict__ i4,
    u16* o0, u16* o1, u16* o2, u16* o3, u16* o4, int n4x, int n4w) {
  const int seg = blockIdx.y;
  const float* in = (seg == 0) ? i0 : (seg == 1) ? i1 : (seg == 2) ? i2 : (seg == 3) ? i3 : i4;
  u16* out = (seg == 0) ? o0 : (seg == 1) ? o1 : (seg == 2) ? o2 : (seg == 3) ? o3 : o4;
  const int n4 = (seg == 0) ? n4x : n4w;
  int i = blockIdx.x * 256 + threadIdx.x;
  const int stride = gridDim.x * 256;
  for (; i < n4; i += stride) {
    const float4 v = ((const float4*)in)[i];
    u16x4 o;
    o.x = f2bf(v.x); o.y = f2bf(v.y); o.z = f2bf(v.z); o.w = f2bf(v.w);
    ((u16x4*)out)[i] = o;
  }
}

// ---------------- GEMM: C[M,N] = A[M,K] * Bt[N,K]^T + bias[N] ----------------
// blockIdx.z selects among 3 (Bt, bias, C) triples -> QKV fused in one launch.
template <int OUT_F32>
__global__ __launch_bounds__(256) void k_gemm_bias(
    const u16* __restrict__ A,
    const u16* __restrict__ Bt0, const u16* __restrict__ Bt1, const u16* __restrict__ Bt2,
    const float* __restrict__ b0, const float* __restrict__ b1, const float* __restrict__ b2,
    u16* __restrict__ C0, u16* __restrict__ C1, u16* __restrict__ C2,
    float* __restrict__ Cf, int M, int N, int K)
{
  const int z = blockIdx.z;
  const u16* Bt = (z == 0) ? Bt0 : (z == 1) ? Bt1 : Bt2;
  const float* bias = (z == 0) ? b0 : (z == 1) ? b1 : b2;
  u16* Cb = (z == 0) ? C0 : (z == 1) ? C1 : C2;

  __shared__ u16 As[128 * 64];
  __shared__ u16 Bs[128 * 64];
  const int tid = threadIdx.x;
  const int lane = tid & 63;
  const int wid = tid >> 6;
  const int fr = lane & 15;
  const int fg = lane >> 4;
  const int wr = wid >> 1, wc = wid & 1;
  const long row0 = (long)blockIdx.x * 128;
  const long col0 = (long)blockIdx.y * 128;

  f32x4 acc[4][4] = {};

  for (int k0 = 0; k0 < K; k0 += 64) {
    __syncthreads();
#pragma unroll
    for (int i = 0; i < 4; ++i) {
      const int chunk = (wid * 4 + i) * 64 + lane;
      const int r = chunk >> 3;
      const int c = (chunk & 7) << 3;
      gload16(A + (row0 + r) * (long)K + k0 + c, &As[(wid * 4 + i) * 512]);
      gload16(Bt + (col0 + r) * (long)K + k0 + c, &Bs[(wid * 4 + i) * 512]);
    }
    __syncthreads();

#pragma unroll
    for (int kc = 0; kc < 2; ++kc) {
      bf16x8 a[4], b[4];
#pragma unroll
      for (int i = 0; i < 4; ++i)
        a[i] = *(const bf16x8*)&As[(wr * 64 + i * 16 + fr) * 64 + kc * 32 + fg * 8];
#pragma unroll
      for (int j = 0; j < 4; ++j)
        b[j] = *(const bf16x8*)&Bs[(wc * 64 + j * 16 + fr) * 64 + kc * 32 + fg * 8];
#pragma unroll
      for (int i = 0; i < 4; ++i)
#pragma unroll
        for (int j = 0; j < 4; ++j)
          acc[i][j] = __builtin_amdgcn_mfma_f32_16x16x32_bf16(a[i], b[j], acc[i][j], 0, 0, 0);
    }
  }

#pragma unroll
  for (int j = 0; j < 4; ++j) {
    const long cN = col0 + wc * 64 + j * 16 + fr;
    const float bv = bias[cN];
#pragma unroll
    for (int i = 0; i < 4; ++i) {
      const long rM = row0 + wr * 64 + i * 16 + fg * 4;
#pragma unroll
      for (int reg = 0; reg < 4; ++reg) {
        const float v = acc[i][j][reg] + bv;
        if (OUT_F32) Cf[(rM + reg) * N + cN] = v;
        else         Cb[(rM + reg) * N + cN] = f2bf(v);
      }
    }
  }
}

// ---------------- V transpose: V[b][s][h*128+d] -> Vt[(b*16+h)*128+d][s] ----------------
__global__ __launch_bounds__(256) void k_transpose_v(const u16* __restrict__ V,
                                                     u16* __restrict__ Vt) {
  __shared__ u16 t[64][68];
  const int bh = blockIdx.z;
  const long s0 = (long)blockIdx.x * 64;
  const long d0 = (long)blockIdx.y * 64;
  const int tid = threadIdx.x;
  const long rowbase = (long)(bh >> 4) * 2048;
  const int hcol = (bh & 15) * 128;
#pragma unroll
  for (int i = 0; i < 4; ++i) {
    const int v = tid + i * 256;
    const int r = v >> 4, c4 = (v & 15) << 2;
    const u16x4 val = *(const u16x4*)&V[(rowbase + s0 + r) * 2048 + hcol + d0 + c4];
    *(u16x4*)&t[r][c4] = val;
  }
  __syncthreads();
#pragma unroll
  for (int i = 0; i < 4; ++i) {
    const int v = tid + i * 256;
    const int dr = v >> 4, s4 = (v & 15) << 2;
    u16x4 o;
    o.x = t[s4 + 0][dr]; o.y = t[s4 + 1][dr]; o.z = t[s4 + 2][dr]; o.w = t[s4 + 3][dr];
    *(u16x4*)&Vt[((long)bh * 128 + d0 + dr) * 2048 + s0 + s4] = o;
  }
}

// ---------------- causal flash attention v3 ----------------
// 256 blocks x 512 threads. Block handles q-blocks bx and 15-bx of 128 rows (34 kv-steps).
// 8 waves x 16 q-rows. KV tiles LDS double-buffered, XOR-swizzled (chunk ^= row&7),
// inverse swizzle on global source. XCD work swizzle: blocks of one head share L%8.
// log2-domain softmax + defer-max (THR=8). Mask only on the <=2 boundary steps/wave.
__global__ __launch_bounds__(512) void k_flash_attn(
    const u16* __restrict__ Q, const u16* __restrict__ K, const u16* __restrict__ Vt,
    u16* __restrict__ O)
{
  __shared__ alignas(16) u16 Kt[2][8192];    // [64 kv][128 d], swizzled
  __shared__ alignas(16) u16 Vtt[2][8192];   // [128 d][64 s], swizzled
  __shared__ alignas(16) u16 Plds[8][16][72];

  const int tid = threadIdx.x;
  const int lane = tid & 63, wid = tid >> 6;
  const int fr = lane & 15, fg = lane >> 4;

  // XCD swizzle: bijective digit mix; all 8 blocks of one bh share (L & 7) -> same XCD.
  const int L = blockIdx.x;
  const int bh = (L & 7) * 4 + ((L >> 3) & 3);
  const int bx = L >> 5;

  const long rowbase = (long)(bh >> 4) * 2048;
  const int hcol = (bh & 15) * 128;
  const u16* Kg = K + rowbase * 2048 + hcol;
  const u16* Vg = Vt + (long)bh * 128 * 2048;
  const float scale2 = 0.08838834764831845f * 1.44269504089f;  // 1/sqrt(128) * log2(e)

  // staging chunk assignment: 1024 chunks/tile, 512 threads -> 2 each
  int kR[2], kC[2], vR[2], vC[2];
#pragma unroll
  for (int i = 0; i < 2; ++i) {
    const int chunk = (wid * 2 + i) * 64 + lane;
    kR[i] = chunk >> 4;                              // K: 16 chunks/row
    kC[i] = ((chunk & 15) ^ (kR[i] & 7)) << 3;
    vR[i] = chunk >> 3;                              // V: 8 chunks/row
    vC[i] = ((chunk & 7) ^ (vR[i] & 7)) << 3;
  }

  // hoisted swizzled LDS read offsets (u16 units); inner loops add const imm
  const int sw = fr & 7;
  int kbase[4], vbase[2];
#pragma unroll
  for (int c = 0; c < 4; ++c) kbase[c] = fr * 128 + (((c * 4 + fg) ^ sw) << 3);
#pragma unroll
  for (int kc = 0; kc < 2; ++kc) vbase[kc] = fr * 64 + (((kc * 4 + fg) ^ sw) << 3);

  for (int pass = 0; pass < 2; ++pass) {
    const int qblk = pass ? (15 - bx) : bx;
    const int n = 2 * (qblk + 1);
    const int q_lo = qblk * 128 + wid * 16;          // wave's first q row

    bf16x8 qf[4];
#pragma unroll
    for (int c = 0; c < 4; ++c)
      qf[c] = *(const bf16x8*)&Q[(rowbase + q_lo + fr) * 2048 + hcol + c * 32 + fg * 8];

    f32x4 oacc[8] = {};
    float m_run[4], l_run[4];
#pragma unroll
    for (int r = 0; r < 4; ++r) { m_run[r] = -1e30f; l_run[r] = 0.0f; }

    // prologue: stage kv-tile 0 into buffer 0
#pragma unroll
    for (int i = 0; i < 2; ++i) {
      gload16(Kg + (long)kR[i] * 2048 + kC[i], &Kt[0][(wid * 2 + i) * 512]);
      gload16(Vg + (long)vR[i] * 2048 + vC[i], &Vtt[0][(wid * 2 + i) * 512]);
    }

    int cur = 0;
    for (int j = 0; j < n; ++j) {
      if (j + 1 < n) {
        const long kv = (long)(j + 1) * 64;
#pragma unroll
        for (int i = 0; i < 2; ++i) {
          gload16(Kg + (kv + kR[i]) * 2048 + kC[i], &Kt[cur ^ 1][(wid * 2 + i) * 512]);
          gload16(Vg + (long)vR[i] * 2048 + kv + vC[i], &Vtt[cur ^ 1][(wid * 2 + i) * 512]);
        }
        asm volatile("s_waitcnt vmcnt(4)" ::: "memory");
      } else {
        asm volatile("s_waitcnt vmcnt(0)" ::: "memory");
      }
      __builtin_amdgcn_s_barrier();
      __builtin_amdgcn_sched_barrier(0);

      const int kvlo = j * 64;
      const bool skip = (kvlo >= q_lo + 16);         // tile fully above diagonal for this wave
      if (!skip) {
        const bool needmask = (kvlo + 63 > q_lo);

        // ---- QK^T ----
        f32x4 st[4] = {};
        const u16* kt = Kt[cur];
#pragma unroll
        for (int t = 0; t < 4; ++t)
#pragma unroll
          for (int c = 0; c < 4; ++c) {
            const bf16x8 kf = *(const bf16x8*)&kt[kbase[c] + t * 2048];
            st[t] = __builtin_amdgcn_mfma_f32_16x16x32_bf16(qf[c], kf, st[t], 0, 0, 0);
          }

        // ---- scale into log2 domain (+ mask on boundary step only) + row max ----
        float pmax[4] = {-1e30f, -1e30f, -1e30f, -1e30f};
        if (needmask) {
#pragma unroll
          for (int t = 0; t < 4; ++t) {
            const int kg = kvlo + t * 16 + fr;
#pragma unroll
            for (int r = 0; r < 4; ++r) {
              const int qg = q_lo + fg * 4 + r;
              const float v = (kg <= qg) ? st[t][r] * scale2 : -1e30f;
              st[t][r] = v;
              pmax[r] = fmaxf(pmax[r], v);
            }
          }
        } else {
#pragma unroll
          for (int t = 0; t < 4; ++t)
#pragma unroll
            for (int r = 0; r < 4; ++r) {
              const float v = st[t][r] * scale2;
              st[t][r] = v;
              pmax[r] = fmaxf(pmax[r], v);
            }
        }
#pragma unroll
        for (int d = 1; d < 16; d <<= 1)
#pragma unroll
          for (int r = 0; r < 4; ++r) pmax[r] = fmaxf(pmax[r], __shfl_xor(pmax[r], d));

        // ---- defer-max: rescale only when max grew past THR=8 (log2 units) ----
        const int ok = (pmax[0] <= m_run[0] + 8.f) & (pmax[1] <= m_run[1] + 8.f) &
                       (pmax[2] <= m_run[2] + 8.f) & (pmax[3] <= m_run[3] + 8.f);
        if (!__all(ok)) {
#pragma unroll
          for (int r = 0; r < 4; ++r) {
            const float nm = fmaxf(m_run[r], pmax[r]);
            const float al = exp2f(m_run[r] - nm);
            l_run[r] *= al;
            m_run[r] = nm;
#pragma unroll
            for (int dt = 0; dt < 8; ++dt) oacc[dt][r] *= al;
          }
        }

        // ---- P = exp2(s - m), row sum ----
        float lsum[4] = {0.f, 0.f, 0.f, 0.f};
#pragma unroll
        for (int t = 0; t < 4; ++t)
#pragma unroll
          for (int r = 0; r < 4; ++r) {
            const float p = exp2f(st[t][r] - m_run[r]);
            st[t][r] = p;
            lsum[r] += p;
          }
#pragma unroll
        for (int d = 1; d < 16; d <<= 1)
#pragma unroll
          for (int r = 0; r < 4; ++r) lsum[r] += __shfl_xor(lsum[r], d);
#pragma unroll
        for (int r = 0; r < 4; ++r) l_run[r] += lsum[r];

        // ---- P (C/D layout) -> per-wave LDS in A-operand layout ----
#pragma unroll
        for (int t = 0; t < 4; ++t)
#pragma unroll
          for (int r = 0; r < 4; ++r)
            Plds[wid][fg * 4 + r][t * 16 + fr] = f2bf(st[t][r]);
        asm volatile("s_waitcnt lgkmcnt(0)" ::: "memory");
        __builtin_amdgcn_sched_barrier(0);

        // ---- O += P * V ----
        const u16* vt = Vtt[cur];
#pragma unroll
        for (int kc = 0; kc < 2; ++kc) {
          const bf16x8 pf = *(const bf16x8*)&Plds[wid][fr][kc * 32 + fg * 8];
#pragma unroll
          for (int dt = 0; dt < 8; ++dt) {
            const bf16x8 vf = *(const bf16x8*)&vt[vbase[kc] + dt * 1024];
            oacc[dt] = __builtin_amdgcn_mfma_f32_16x16x32_bf16(pf, vf, oacc[dt], 0, 0, 0);
          }
        }
      }

      asm volatile("" ::: "memory");
      __builtin_amdgcn_s_barrier();   // all waves done reading buf[cur]
      cur ^= 1;
    }

    float inv[4];
#pragma unroll
    for (int r = 0; r < 4; ++r) inv[r] = 1.0f / l_run[r];
#pragma unroll
    for (int dt = 0; dt < 8; ++dt)
#pragma unroll
      for (int r = 0; r < 4; ++r)
        O[(rowbase + q_lo + fg * 4 + r) * 2048 + hcol + dt * 16 + fr] = f2bf(oacc[dt][r] * inv[r]);
  }
}

extern "C" void kernel_launch(void* const* d_in, const int* in_sizes, int n_in,
                              void* d_out, int out_size, void* d_ws, size_t ws_size,
                              hipStream_t stream) {
  const float* x  = (const float*)d_in[0];
  const float* Wq = (const float*)d_in[1];
  const float* bq = (const float*)d_in[2];
  const float* Wk = (const float*)d_in[3];
  const float* bk = (const float*)d_in[4];
  const float* Wv = (const float*)d_in[5];
  const float* bv = (const float*)d_in[6];
  const float* Wo = (const float*)d_in[7];
  const float* bo = (const float*)d_in[8];
  float* out = (float*)d_out;

  const int M = 4096, N = 2048, Kd = 2048;
  char* ws = (char*)d_ws;
  const size_t SZ_X = 16777216;   // 8M bf16
  const size_t SZ_W = 8388608;    // 4M bf16
  u16* xb  = (u16*)(ws);
  u16* wqb = (u16*)(ws + SZ_X);
  u16* wkb = (u16*)(ws + SZ_X + 1 * SZ_W);
  u16* wvb = (u16*)(ws + SZ_X + 2 * SZ_W);
  u16* wob = (u16*)(ws + SZ_X + 3 * SZ_W);
  u16* Qb  = (u16*)(ws + 1 * SZ_X + 4 * SZ_W);
  u16* Kb  = (u16*)(ws + 2 * SZ_X + 4 * SZ_W);
  u16* Vb  = (u16*)(ws + 3 * SZ_X + 4 * SZ_W);
  u16* Vtb = (u16*)(ws + 4 * SZ_X + 4 * SZ_W);
  u16* Ob  = Vb;   // V dead after transpose; reuse for attention output

  k_f2bf5<<<dim3(1024, 5), 256, 0, stream>>>(x, Wq, Wk, Wv, Wo,
                                             xb, wqb, wkb, wvb, wob,
                                             8388608 / 4, 4194304 / 4);

  // fused QKV projections: blockIdx.z picks (W, bias, out)
  k_gemm_bias<0><<<dim3(M / 128, N / 128, 3), 256, 0, stream>>>(
      xb, wqb, wkb, wvb, bq, bk, bv, Qb, Kb, Vb, nullptr, M, N, Kd);

  k_transpose_v<<<dim3(32, 2, 32), 256, 0, stream>>>(Vb, Vtb);

  k_flash_attn<<<256, 512, 0, stream>>>(Qb, Kb, Vtb, Ob);

  // output projection (fp32 out)
  k_gemm_bias<1><<<dim3(M / 128, N / 128, 1), 256, 0, stream>>>(
      Ob, wob, wob, wob, bo, bo, bo, nullptr, nullptr, nullptr, out, M, N, Kd);
}